// Round 7
// baseline (215.747 us; speedup 1.0000x reference)
//
#include <hip/hip_runtime.h>

// LinearMemoryBackend: y_t = M_t q_t, M_t = sum_{s<=t} v_s k_s^T
// Chunked MFMA bf16, 2-kernel pipeline.
// R7 probe: dur = F + n*P'; F~77us harness floor, P' = pipeline cost.
// R8: k2 split-half scan -> P' 32.5 -> 29.9us.
// R9: traffic-neutral KB/VB swap -> ~0; pipeline is BYTES-bound ~6TB/s.
// R10: CH 64->128 (-27MB scratch) -> P' 27.1us.
// R11: k2 deleted; exclusive prefix fused into k_output (bit-identical M).
// R12: r11 resubmit after infra failure + FIX: fused-prefix LDS write must
//      XOR-address EACH 4-element quad ((e0)^x and (e0+4)^x) -- j bit2 and
//      sigma bit2 overlap, so contiguous mf/mf+4 was wrong for odd (row&7).
// ws: S @0 (4.2MB), KB @56MiB (8.4MB), VB @72MiB (8.4MB).
// 5x replay instrument retained: P' = (dur - 77.4)/5. Final round will be 1x.

#define B_   2
#define T_   4096
#define H_   8
#define D_   64
#define CH   128
#define NC   (T_ / CH)
#define BH   (B_ * H_)
#define SROW (H_ * D_)
#define SB   (T_ * H_ * D_)

typedef __attribute__((ext_vector_type(4))) float f32x4;
typedef __attribute__((ext_vector_type(8))) short bf16x8;

__device__ inline unsigned short f2bf(float f) {
  unsigned int u = __builtin_bit_cast(unsigned int, f);
  unsigned int r = (u + 0x7FFFu + ((u >> 16) & 1u)) >> 16;
  return (unsigned short)r;
}
__device__ inline float bf2f(unsigned short b) {
  unsigned int u = ((unsigned int)b) << 16;
  return __builtin_bit_cast(float, u);
}
__device__ inline void st4bf(unsigned short* p, float a, float b, float c, float d) {
  union { uint2 u; unsigned short s[4]; } x;
  x.s[0] = f2bf(a); x.s[1] = f2bf(b); x.s[2] = f2bf(c); x.s[3] = f2bf(d);
  *(uint2*)p = x.u;
}
__device__ inline bf16x8 ld128(const unsigned short* p) {
  union { uint4 u; bf16x8 v; } x;
  x.u = *(const uint4*)p;
  return x.v;
}
// unpack 8 consecutive packed (hi<<16|lo) u32 into hi/lo bf16x8 B-frags (r5-validated)
__device__ inline void unpackM(const uint4 a, const uint4 b, bf16x8& hi, bf16x8& lo) {
  unsigned xs[8] = { a.x, a.y, a.z, a.w, b.x, b.y, b.z, b.w };
  union { unsigned u[4]; bf16x8 v; } H, L;
#pragma unroll
  for (int i = 0; i < 4; ++i) {
    unsigned p0 = xs[2 * i], p1 = xs[2 * i + 1];
    H.u[i] = (p0 >> 16) | (p1 & 0xffff0000u);
    L.u[i] = (p0 & 0xffffu) | (p1 << 16);
  }
  hi = H.v; lo = L.v;
}

// fragment slot orderings (lane l: m = l&15, q = l>>4)
//  row-access operands: slot_A = m*4+q
//  transpose-staged:    slot_V = (m&3)*16 + q*4 + (m>>2)

// ---------------- kernel 1: chunk outer-product sums + bf16 K/V fragment images ----------------
// 512 threads (8 waves), 512 blocks. Wave w: rows 16*(w>>1) of S, col-tiles {2*(w&1), 2*(w&1)+1}.
__global__ __launch_bounds__(512) void k_chunksum(const float* __restrict__ kp,
                                                  const float* __restrict__ vp,
                                                  unsigned short* __restrict__ Sp,
                                                  unsigned short* __restrict__ KBp,
                                                  unsigned short* __restrict__ VBp) {
  const int bid = blockIdx.x;
  const int c   = bid & 31;
  const int bh  = bid >> 5;
  const int b   = bh >> 3, h = bh & 7;
  const size_t base = (size_t)b * SB + (size_t)h * D_ + (size_t)(c * CH) * SROW;

  __shared__ __align__(16) unsigned short KT[8192], VT[8192];   // 16 KB each (64 x 128)

  const int tid = threadIdx.x;
  const int l = tid & 63, w = tid >> 6;        // w 0..7
  const int mlan = l & 15, qlan = l >> 4;

  unsigned short* KBg = KBp + (size_t)bid * 8192;
  unsigned short* VBg = VBp + (size_t)bid * 8192;

  // transposed bf16 staging (4x4 register transpose) + global fragment images
  {
    const int t0 = (tid >> 4) * 4;             // 0..124
    const int m0 = tid & 15;
    const int qs = (t0 >> 3) & 3, kbs = t0 >> 5, j0 = t0 & 4;   // kbs 0..3
    float4 kr[4], vr[4];
#pragma unroll
    for (int i = 0; i < 4; ++i) {
      const size_t g = base + (size_t)(t0 + i) * SROW + 4 * m0;
      kr[i] = *(const float4*)(kp + g);
      vr[i] = *(const float4*)(vp + g);
    }
    // K row-form image (== k3 KF layout): row t, cols 4m0..4m0+3
    {
      const int kb = m0 >> 3, qq = (m0 & 7) >> 1, j0k = (m0 & 1) * 4;
#pragma unroll
      for (int i = 0; i < 4; ++i) {
        const int t = t0 + i;
        const int addrK = (((t >> 4) * 2 + kb) * 64 + ((t & 15) * 4 + qq)) * 8 + j0k;
        st4bf(KBg + addrK, kr[i].x, kr[i].y, kr[i].z, kr[i].w);
      }
    }
#pragma unroll
    for (int r = 0; r < 4; ++r) {
      const int d = 4 * m0 + r;
      const int slot = r * 16 + qs * 4 + (m0 & 3);
      const int addr = (((d >> 4) * 4 + kbs) * 64 + slot) * 8 + j0;   // 4 s-blocks
      st4bf(KT + addr, ((const float*)&kr[0])[r], ((const float*)&kr[1])[r],
                       ((const float*)&kr[2])[r], ((const float*)&kr[3])[r]);
      st4bf(VT + addr, ((const float*)&vr[0])[r], ((const float*)&vr[1])[r],
                       ((const float*)&vr[2])[r], ((const float*)&vr[3])[r]);
      // V transposed image (== k3 VF layout, same formula as VT)
      st4bf(VBg + addr, ((const float*)&vr[0])[r], ((const float*)&vr[1])[r],
                        ((const float*)&vr[2])[r], ((const float*)&vr[3])[r]);
    }
  }
  __syncthreads();

  const int rslot = ((mlan & 3) << 4) + (qlan << 2) + (mlan >> 2);
  const int wr = w >> 1, wc = w & 1;
  bf16x8 av[4];
#pragma unroll
  for (int kb = 0; kb < 4; ++kb)
    av[kb] = ld128(VT + ((wr * 4 + kb) * 64 + rslot) * 8);

  unsigned short* Sc = Sp + (size_t)bid * 4096;
#pragma unroll
  for (int teh = 0; teh < 2; ++teh) {
    const int te = wc * 2 + teh;
    f32x4 acc = {0.f, 0.f, 0.f, 0.f};
#pragma unroll
    for (int kb = 0; kb < 4; ++kb) {
      bf16x8 bk = ld128(KT + ((te * 4 + kb) * 64 + rslot) * 8);
      acc = __builtin_amdgcn_mfma_f32_16x16x32_bf16(av[kb], bk, acc, 0, 0, 0);
    }
#pragma unroll
    for (int r = 0; r < 4; ++r)
      Sc[(16 * wr + 4 * qlan + r) * 64 + 16 * te + mlan] = f2bf(acc[r]);
  }
}

// ---------------- kernel 2: y = (QK^T masked)V + Q*M, prefix fused ----------------
// 512 threads (8 waves), 512 blocks; wave w owns rows 16w..16w+15 of the 128-row chunk.
// Fused exclusive prefix: thread owns 8 consecutive M elements; sums S tiles c'<c
// from global (L2/L3-resident) with k2's exact fp32 add order -> bit-identical M;
// packs hi|lo and ds_writes MF per-QUAD at the sigma-swizzled addresses.
__global__ __launch_bounds__(512, 4) void k_output(const float* __restrict__ qp,
                                                   const unsigned short* __restrict__ KBp,
                                                   const unsigned short* __restrict__ VBp,
                                                   const unsigned short* __restrict__ Sp,
                                                   float* __restrict__ yp) {
  const int bid = blockIdx.x;
  const int c   = bid & 31;
  const int bh  = bid >> 5;
  const int b   = bh >> 3, h = bh & 7;
  const size_t base = (size_t)b * SB + (size_t)h * D_ + (size_t)(c * CH) * SROW;

  // 64 KB total -> 2 blocks/CU (16 waves/CU)
  __shared__ __align__(16) unsigned short KF[8192], VF[8192], PS[8192];
  __shared__ __align__(16) unsigned MF[4096];

  const int tid = threadIdx.x;
  const int l = tid & 63, w = tid >> 6;        // w 0..7
  const int mlan = l & 15, qlan = l >> 4;

  // async K fragment image -> KF (16 KB linear)
#pragma unroll
  for (int i = 0; i < 2; ++i) {
    const unsigned short* g = KBp + (size_t)bid * 8192 + (w * 2 + i) * 512 + l * 8;
    __builtin_amdgcn_global_load_lds(
        (const __attribute__((address_space(1))) unsigned short*)g,
        (__attribute__((address_space(3))) unsigned short*)(KF + (w * 2 + i) * 512),
        16, 0, 0);
  }
  // async V fragment image -> VF (16 KB linear)
#pragma unroll
  for (int i = 0; i < 2; ++i) {
    const unsigned short* g = VBp + (size_t)bid * 8192 + (w * 2 + i) * 512 + l * 8;
    __builtin_amdgcn_global_load_lds(
        (const __attribute__((address_space(1))) unsigned short*)g,
        (__attribute__((address_space(3))) unsigned short*)(VF + (w * 2 + i) * 512),
        16, 0, 0);
  }

  // ---- fused exclusive prefix over chunks: MF[sigma(e)] = pack(run_e) ----
  {
    const int e0 = tid * 8;                    // 8 consecutive elements
    const unsigned short* sp = Sp + (size_t)bh * (NC * 4096) + e0;
    float run[8] = {0.f, 0.f, 0.f, 0.f, 0.f, 0.f, 0.f, 0.f};
    const int nb4 = c >> 2;                    // full 4-chunk batches
    for (int b4 = 0; b4 < nb4; ++b4) {
      uint4 sv[4];
#pragma unroll
      for (int i = 0; i < 4; ++i)
        sv[i] = *(const uint4*)(sp + (size_t)(b4 * 4 + i) * 4096);
#pragma unroll
      for (int i = 0; i < 4; ++i) {
        const unsigned short* s8 = (const unsigned short*)&sv[i];
#pragma unroll
        for (int j = 0; j < 8; ++j) run[j] += bf2f(s8[j]);
      }
    }
    for (int c2 = nb4 * 4; c2 < c; ++c2) {     // remainder chunks (<=3)
      uint4 sv = *(const uint4*)(sp + (size_t)c2 * 4096);
      const unsigned short* s8 = (const unsigned short*)&sv;
#pragma unroll
      for (int j = 0; j < 8; ++j) run[j] += bf2f(s8[j]);
    }
    unsigned pk[8];
#pragma unroll
    for (int j = 0; j < 8; ++j) {
      const unsigned short hi = f2bf(run[j]);
      const unsigned short lo = f2bf(run[j] - bf2f(hi));
      pk[j] = ((unsigned)hi << 16) | (unsigned)lo;
    }
    // sigma(e) = e ^ (((e>>6)&7)<<2) XORs bits 2-4; j occupies bits 0-2, so
    // each 4-element QUAD stays contiguous but the quads themselves move:
    // quad0 -> (e0)^x, quad1 -> (e0+4)^x  (NOT (e0^x)+4 -- bit-2 overlap! r12 fix)
    const int x = ((e0 >> 6) & 7) << 2;        // uniform across the 8
    *(uint4*)(MF + ((e0    ) ^ x)) = *(const uint4*)&pk[0];
    *(uint4*)(MF + ((e0 + 4) ^ x)) = *(const uint4*)&pk[4];
  }

  // Q A-frags direct from global: aq[kb][j] = Q[16w+mlan][32kb+8qlan+j]
  bf16x8 aq[2];
  {
    const float* qrow = qp + base + (size_t)(16 * w + mlan) * SROW + 8 * qlan;
#pragma unroll
    for (int kb = 0; kb < 2; ++kb) {
      float4 a0 = *(const float4*)(qrow + 32 * kb);
      float4 a1 = *(const float4*)(qrow + 32 * kb + 4);
      union { unsigned short s[8]; bf16x8 v; } P;
      P.s[0] = f2bf(a0.x); P.s[1] = f2bf(a0.y); P.s[2] = f2bf(a0.z); P.s[3] = f2bf(a0.w);
      P.s[4] = f2bf(a1.x); P.s[5] = f2bf(a1.y); P.s[6] = f2bf(a1.z); P.s[7] = f2bf(a1.w);
      aq[kb] = P.v;
    }
  }
  __syncthreads();   // drains DMAs (implicit vmcnt/lgkm) + orders MF writes

  const int rslot = ((mlan & 3) << 4) + (qlan << 2) + (mlan >> 2);
  unsigned short* PSW = PS + w * 1024;

  f32x4 accY[4];
#pragma unroll
  for (int td = 0; td < 4; ++td) accY[td] = (f32x4){0.f, 0.f, 0.f, 0.f};

  // ---- phase A: s-tiles ts = 0..3 (cols 0..63) ----
  {
    f32x4 accP[4];
#pragma unroll
    for (int ts = 0; ts < 4; ++ts) accP[ts] = (f32x4){0.f, 0.f, 0.f, 0.f};
#pragma unroll
    for (int ts = 0; ts < 4; ++ts) {
      if (ts <= w) {
#pragma unroll
        for (int kb = 0; kb < 2; ++kb) {
          bf16x8 bk = ld128(KF + ((ts * 2 + kb) * 64 + (mlan * 4 + qlan)) * 8);
          accP[ts] = __builtin_amdgcn_mfma_f32_16x16x32_bf16(aq[kb], bk, accP[ts], 0, 0, 0);
        }
      }
    }
    // diagonal mask (only waves 0..3 have their diagonal in phase A)
#pragma unroll
    for (int ts = 0; ts < 4; ++ts)
      if (ts == w) {
#pragma unroll
        for (int r = 0; r < 4; ++r)
          if (mlan > qlan * 4 + r) accP[ts][r] = 0.f;
      }
    // P strip -> PS octet layout (wave-private)
#pragma unroll
    for (int ts = 0; ts < 4; ++ts)
#pragma unroll
      for (int r = 0; r < 4; ++r)
        PSW[((2 * ts + (mlan >> 3)) * 16 + 4 * qlan + r) * 8 + (mlan & 7)] =
            f2bf(accP[ts][r]);
    bf16x8 ap[2];
#pragma unroll
    for (int sb = 0; sb < 2; ++sb)
      ap[sb] = ld128(PSW + ((4 * sb + qlan) * 16 + mlan) * 8);
    // Y += P[:,0:64] V[0:64,:]
#pragma unroll
    for (int td = 0; td < 4; ++td)
#pragma unroll
      for (int sb = 0; sb < 2; ++sb) {
        bf16x8 bv = ld128(VF + ((td * 4 + sb) * 64 + rslot) * 8);
        accY[td] = __builtin_amdgcn_mfma_f32_16x16x32_bf16(ap[sb], bv, accY[td], 0, 0, 0);
      }
  }

  // ---- phase B: s-tiles ts = 4..7 (cols 64..127); causally zero for waves w<4 ----
  if (w >= 4) {
    f32x4 accP[4];
#pragma unroll
    for (int ts = 0; ts < 4; ++ts) accP[ts] = (f32x4){0.f, 0.f, 0.f, 0.f};
#pragma unroll
    for (int tsi = 0; tsi < 4; ++tsi) {
      const int ts = tsi + 4;
      if (ts <= w) {
#pragma unroll
        for (int kb = 0; kb < 2; ++kb) {
          bf16x8 bk = ld128(KF + ((ts * 2 + kb) * 64 + (mlan * 4 + qlan)) * 8);
          accP[tsi] = __builtin_amdgcn_mfma_f32_16x16x32_bf16(aq[kb], bk, accP[tsi], 0, 0, 0);
        }
      }
    }
#pragma unroll
    for (int tsi = 0; tsi < 4; ++tsi)
      if (tsi + 4 == w) {
#pragma unroll
        for (int r = 0; r < 4; ++r)
          if (mlan > qlan * 4 + r) accP[tsi][r] = 0.f;
      }
    // overwrite wave-private PS (same-wave LDS ordering guarantees correctness)
#pragma unroll
    for (int tsi = 0; tsi < 4; ++tsi)
#pragma unroll
      for (int r = 0; r < 4; ++r)
        PSW[((2 * tsi + (mlan >> 3)) * 16 + 4 * qlan + r) * 8 + (mlan & 7)] =
            f2bf(accP[tsi][r]);
    bf16x8 ap[2];
#pragma unroll
    for (int sb = 0; sb < 2; ++sb)
      ap[sb] = ld128(PSW + ((4 * sb + qlan) * 16 + mlan) * 8);
    // Y += P[:,64:128] V[64:128,:]  (VF s-blocks 2..3)
#pragma unroll
    for (int td = 0; td < 4; ++td)
#pragma unroll
      for (int sb = 0; sb < 2; ++sb) {
        bf16x8 bv = ld128(VF + ((td * 4 + 2 + sb) * 64 + rslot) * 8);
        accY[td] = __builtin_amdgcn_mfma_f32_16x16x32_bf16(ap[sb], bv, accY[td], 0, 0, 0);
      }
  }

  // matmul3: Y += Q * (Mhi + Mlo), M B-frags from swizzled LDS (64x64 tile, unchanged)
  const int m7 = mlan & 7;
#pragma unroll
  for (int td = 0; td < 4; ++td)
#pragma unroll
    for (int kb = 0; kb < 2; ++kb) {
      const int mb = (16 * td + mlan) * 64 + kb * 32 + ((qlan ^ (m7 >> 1)) << 3);
      const uint4 va = *(const uint4*)(MF + mb + ((m7 & 1) << 2));        // j = 0..3
      const uint4 vb = *(const uint4*)(MF + mb + (((m7 & 1) ^ 1) << 2));  // j = 4..7
      bf16x8 bmh, bml;
      unpackM(va, vb, bmh, bml);
      accY[td] = __builtin_amdgcn_mfma_f32_16x16x32_bf16(aq[kb], bmh, accY[td], 0, 0, 0);
      accY[td] = __builtin_amdgcn_mfma_f32_16x16x32_bf16(aq[kb], bml, accY[td], 0, 0, 0);
    }

#pragma unroll
  for (int td = 0; td < 4; ++td)
#pragma unroll
    for (int r = 0; r < 4; ++r)
      yp[base + (size_t)(16 * w + 4 * qlan + r) * SROW + 16 * td + mlan] = accY[td][r];
}

extern "C" void kernel_launch(void* const* d_in, const int* in_sizes, int n_in,
                              void* d_out, int out_size, void* d_ws, size_t ws_size,
                              hipStream_t stream) {
  const float* q = (const float*)d_in[0];
  const float* k = (const float*)d_in[1];
  const float* v = (const float*)d_in[2];
  float* y = (float*)d_out;
  unsigned short* S  = (unsigned short*)d_ws;                        // 4.2 MB bf16
  unsigned short* KB = (unsigned short*)((char*)d_ws + (56u << 20)); // 8.4 MB bf16 frag image
  unsigned short* VB = (unsigned short*)((char*)d_ws + (72u << 20)); // 8.4 MB bf16 frag image

  // 5x replay instrument (idempotent pipeline): P' = (dur - 77.4us)/5.
  // Final submission round will revert to a single pass.
  for (int rep = 0; rep < 5; ++rep) {
    k_chunksum<<<BH * NC, 512, 0, stream>>>(k, v, S, KB, VB);
    k_output  <<<BH * NC, 512, 0, stream>>>(q, KB, VB, S, y);
  }
}

// Round 8
// 104.942 us; speedup vs baseline: 2.0559x; 2.0559x over previous
//
#include <hip/hip_runtime.h>

// LinearMemoryBackend: y_t = M_t q_t, M_t = sum_{s<=t} v_s k_s^T
// FINAL (r13): single-pass r10 pipeline — the best measured variant.
// Session ledger (P' = true pipeline cost via 5x-replay instrument, F~77us harness floor):
//   r6  baseline-polish:            P' = 32.5us
//   r8  k2 split-half scan:         P' = 29.9us  (occupancy fix, 2 waves/SIMD)
//   r9  KB/VB frag images:          ~0   (byte-neutral -> confirmed bytes-bound ~6TB/s)
//   r10 CH 64->128:                 P' = 27.1us  (-27MB scratch round-trip)
//   r12 fused prefix into k_output: P' = 27.7us  (M round-trip saved == L3 S re-reads added; reverted)
// Structure: k1 chunk outer-product sums (S) + pre-packed bf16 K/V fragment
// images (KB row/A-frag == k3 KF layout; VB transposed == VF layout);
// k2 exclusive prefix over chunks (split-half, sigma-swizzled packed hi|lo M);
// k3 y = (QK^T masked)V + Q*(Mhi+Mlo) with K/V/M all via linear global_load_lds.
// ws: S @0 (4.2MB), M @32MiB (8.4MB), KB @56MiB (8.4MB), VB @72MiB (8.4MB).

#define B_   2
#define T_   4096
#define H_   8
#define D_   64
#define CH   128
#define NC   (T_ / CH)
#define BH   (B_ * H_)
#define SROW (H_ * D_)
#define SB   (T_ * H_ * D_)

typedef __attribute__((ext_vector_type(4))) float f32x4;
typedef __attribute__((ext_vector_type(8))) short bf16x8;

__device__ inline unsigned short f2bf(float f) {
  unsigned int u = __builtin_bit_cast(unsigned int, f);
  unsigned int r = (u + 0x7FFFu + ((u >> 16) & 1u)) >> 16;
  return (unsigned short)r;
}
__device__ inline float bf2f(unsigned short b) {
  unsigned int u = ((unsigned int)b) << 16;
  return __builtin_bit_cast(float, u);
}
__device__ inline void st4bf(unsigned short* p, float a, float b, float c, float d) {
  union { uint2 u; unsigned short s[4]; } x;
  x.s[0] = f2bf(a); x.s[1] = f2bf(b); x.s[2] = f2bf(c); x.s[3] = f2bf(d);
  *(uint2*)p = x.u;
}
__device__ inline bf16x8 ld128(const unsigned short* p) {
  union { uint4 u; bf16x8 v; } x;
  x.u = *(const uint4*)p;
  return x.v;
}
// unpack 8 consecutive packed (hi<<16|lo) u32 into hi/lo bf16x8 B-frags (r5-validated)
__device__ inline void unpackM(const uint4 a, const uint4 b, bf16x8& hi, bf16x8& lo) {
  unsigned xs[8] = { a.x, a.y, a.z, a.w, b.x, b.y, b.z, b.w };
  union { unsigned u[4]; bf16x8 v; } H, L;
#pragma unroll
  for (int i = 0; i < 4; ++i) {
    unsigned p0 = xs[2 * i], p1 = xs[2 * i + 1];
    H.u[i] = (p0 >> 16) | (p1 & 0xffff0000u);
    L.u[i] = (p0 & 0xffffu) | (p1 << 16);
  }
  hi = H.v; lo = L.v;
}

// fragment slot orderings (lane l: m = l&15, q = l>>4)
//  row-access operands: slot_A = m*4+q
//  transpose-staged:    slot_V = (m&3)*16 + q*4 + (m>>2)

// ---------------- kernel 1: chunk outer-product sums + bf16 K/V fragment images ----------------
// 512 threads (8 waves), 512 blocks. Wave w: rows 16*(w>>1) of S, col-tiles {2*(w&1), 2*(w&1)+1}.
__global__ __launch_bounds__(512) void k_chunksum(const float* __restrict__ kp,
                                                  const float* __restrict__ vp,
                                                  unsigned short* __restrict__ Sp,
                                                  unsigned short* __restrict__ KBp,
                                                  unsigned short* __restrict__ VBp) {
  const int bid = blockIdx.x;
  const int c   = bid & 31;
  const int bh  = bid >> 5;
  const int b   = bh >> 3, h = bh & 7;
  const size_t base = (size_t)b * SB + (size_t)h * D_ + (size_t)(c * CH) * SROW;

  __shared__ __align__(16) unsigned short KT[8192], VT[8192];   // 16 KB each (64 x 128)

  const int tid = threadIdx.x;
  const int l = tid & 63, w = tid >> 6;        // w 0..7
  const int mlan = l & 15, qlan = l >> 4;

  unsigned short* KBg = KBp + (size_t)bid * 8192;
  unsigned short* VBg = VBp + (size_t)bid * 8192;

  // transposed bf16 staging (4x4 register transpose) + global fragment images
  {
    const int t0 = (tid >> 4) * 4;             // 0..124
    const int m0 = tid & 15;
    const int qs = (t0 >> 3) & 3, kbs = t0 >> 5, j0 = t0 & 4;   // kbs 0..3
    float4 kr[4], vr[4];
#pragma unroll
    for (int i = 0; i < 4; ++i) {
      const size_t g = base + (size_t)(t0 + i) * SROW + 4 * m0;
      kr[i] = *(const float4*)(kp + g);
      vr[i] = *(const float4*)(vp + g);
    }
    // K row-form image (== k3 KF layout): row t, cols 4m0..4m0+3
    {
      const int kb = m0 >> 3, qq = (m0 & 7) >> 1, j0k = (m0 & 1) * 4;
#pragma unroll
      for (int i = 0; i < 4; ++i) {
        const int t = t0 + i;
        const int addrK = (((t >> 4) * 2 + kb) * 64 + ((t & 15) * 4 + qq)) * 8 + j0k;
        st4bf(KBg + addrK, kr[i].x, kr[i].y, kr[i].z, kr[i].w);
      }
    }
#pragma unroll
    for (int r = 0; r < 4; ++r) {
      const int d = 4 * m0 + r;
      const int slot = r * 16 + qs * 4 + (m0 & 3);
      const int addr = (((d >> 4) * 4 + kbs) * 64 + slot) * 8 + j0;   // 4 s-blocks
      st4bf(KT + addr, ((const float*)&kr[0])[r], ((const float*)&kr[1])[r],
                       ((const float*)&kr[2])[r], ((const float*)&kr[3])[r]);
      st4bf(VT + addr, ((const float*)&vr[0])[r], ((const float*)&vr[1])[r],
                       ((const float*)&vr[2])[r], ((const float*)&vr[3])[r]);
      // V transposed image (== k3 VF layout, same formula as VT)
      st4bf(VBg + addr, ((const float*)&vr[0])[r], ((const float*)&vr[1])[r],
                        ((const float*)&vr[2])[r], ((const float*)&vr[3])[r]);
    }
  }
  __syncthreads();

  const int rslot = ((mlan & 3) << 4) + (qlan << 2) + (mlan >> 2);
  const int wr = w >> 1, wc = w & 1;
  bf16x8 av[4];
#pragma unroll
  for (int kb = 0; kb < 4; ++kb)
    av[kb] = ld128(VT + ((wr * 4 + kb) * 64 + rslot) * 8);

  unsigned short* Sc = Sp + (size_t)bid * 4096;
#pragma unroll
  for (int teh = 0; teh < 2; ++teh) {
    const int te = wc * 2 + teh;
    f32x4 acc = {0.f, 0.f, 0.f, 0.f};
#pragma unroll
    for (int kb = 0; kb < 4; ++kb) {
      bf16x8 bk = ld128(KT + ((te * 4 + kb) * 64 + rslot) * 8);
      acc = __builtin_amdgcn_mfma_f32_16x16x32_bf16(av[kb], bk, acc, 0, 0, 0);
    }
#pragma unroll
    for (int r = 0; r < 4; ++r)
      Sc[(16 * wr + 4 * qlan + r) * 64 + 16 * te + mlan] = f2bf(acc[r]);
  }
}

// ---------------- kernel 2: exclusive prefix (bf16 S in, packed hi|lo M out) ----------------
// NC=32, split-half scan (depth 16). 131072 threads = 512 blocks.
// half=1 accumulates its base from chunks 0..15 in the SAME order -> bit-identical M.
// M written sigma-swizzled: sigma(e) = e ^ (((e>>6)&7)<<2).
__global__ __launch_bounds__(256) void k_prefix(const unsigned short* __restrict__ Sp,
                                                unsigned* __restrict__ Mp) {
  const int g = blockIdx.x * 256 + threadIdx.x;   // 0..131071
  const int half = g >> 16;                        // 0 or 1 (wave-uniform)
  const int gg = g & 65535;
  const int bh = gg >> 12, e = gg & 4095;
  const int ep = e ^ (((e >> 6) & 7) << 2);       // sigma(e)
  const unsigned short* sp = Sp + (size_t)bh * (NC * 4096) + e;
  unsigned* mp = Mp + (size_t)bh * (NC * 4096) + ep;
  float run = 0.f;
  if (half) {
    unsigned short sv[16];
#pragma unroll
    for (int i = 0; i < 16; ++i)
      sv[i] = sp[(size_t)i * 4096];
#pragma unroll
    for (int i = 0; i < 16; ++i) run += bf2f(sv[i]);
  }
  const int c0 = half * 16;
  {
    unsigned short sv[16];
#pragma unroll
    for (int i = 0; i < 16; ++i)
      sv[i] = sp[(size_t)(c0 + i) * 4096];
#pragma unroll
    for (int i = 0; i < 16; ++i) {
      const unsigned short hi = f2bf(run);
      const unsigned short lo = f2bf(run - bf2f(hi));
      mp[(size_t)(c0 + i) * 4096] = ((unsigned)hi << 16) | (unsigned)lo;
      run += bf2f(sv[i]);
    }
  }
}

// ---------------- kernel 3: y = (QK^T masked)V + Q*M ----------------
// 512 threads (8 waves), 512 blocks; wave w owns rows 16w..16w+15 of the 128-row chunk.
// Two causal phases over s reusing the wave-private PS region (waves w<4 skip phase B).
__global__ __launch_bounds__(512, 4) void k_output(const float* __restrict__ qp,
                                                   const unsigned short* __restrict__ KBp,
                                                   const unsigned short* __restrict__ VBp,
                                                   const unsigned* __restrict__ Mp,
                                                   float* __restrict__ yp) {
  const int bid = blockIdx.x;
  const int c   = bid & 31;
  const int bh  = bid >> 5;
  const int b   = bh >> 3, h = bh & 7;
  const size_t base = (size_t)b * SB + (size_t)h * D_ + (size_t)(c * CH) * SROW;

  // 64 KB total -> 2 blocks/CU (16 waves/CU)
  __shared__ __align__(16) unsigned short KF[8192], VF[8192], PS[8192];
  __shared__ __align__(16) unsigned MF[4096];

  const int tid = threadIdx.x;
  const int l = tid & 63, w = tid >> 6;        // w 0..7
  const int mlan = l & 15, qlan = l >> 4;

  // async M -> LDS DMA (16 KB linear, sigma-swizzled content)
#pragma unroll
  for (int i = 0; i < 2; ++i) {
    const unsigned* g = Mp + (size_t)bid * 4096 + (w * 2 + i) * 256 + l * 4;
    __builtin_amdgcn_global_load_lds(
        (const __attribute__((address_space(1))) unsigned*)g,
        (__attribute__((address_space(3))) unsigned*)(MF + (w * 2 + i) * 256),
        16, 0, 0);
  }
  // async K fragment image -> KF (16 KB linear)
#pragma unroll
  for (int i = 0; i < 2; ++i) {
    const unsigned short* g = KBp + (size_t)bid * 8192 + (w * 2 + i) * 512 + l * 8;
    __builtin_amdgcn_global_load_lds(
        (const __attribute__((address_space(1))) unsigned short*)g,
        (__attribute__((address_space(3))) unsigned short*)(KF + (w * 2 + i) * 512),
        16, 0, 0);
  }
  // async V fragment image -> VF (16 KB linear)
#pragma unroll
  for (int i = 0; i < 2; ++i) {
    const unsigned short* g = VBp + (size_t)bid * 8192 + (w * 2 + i) * 512 + l * 8;
    __builtin_amdgcn_global_load_lds(
        (const __attribute__((address_space(1))) unsigned short*)g,
        (__attribute__((address_space(3))) unsigned short*)(VF + (w * 2 + i) * 512),
        16, 0, 0);
  }

  // Q A-frags direct from global: aq[kb][j] = Q[16w+mlan][32kb+8qlan+j]
  bf16x8 aq[2];
  {
    const float* qrow = qp + base + (size_t)(16 * w + mlan) * SROW + 8 * qlan;
#pragma unroll
    for (int kb = 0; kb < 2; ++kb) {
      float4 a0 = *(const float4*)(qrow + 32 * kb);
      float4 a1 = *(const float4*)(qrow + 32 * kb + 4);
      union { unsigned short s[8]; bf16x8 v; } P;
      P.s[0] = f2bf(a0.x); P.s[1] = f2bf(a0.y); P.s[2] = f2bf(a0.z); P.s[3] = f2bf(a0.w);
      P.s[4] = f2bf(a1.x); P.s[5] = f2bf(a1.y); P.s[6] = f2bf(a1.z); P.s[7] = f2bf(a1.w);
      aq[kb] = P.v;
    }
  }
  __syncthreads();   // implicit vmcnt(0) drains all DMAs + Q loads

  const int rslot = ((mlan & 3) << 4) + (qlan << 2) + (mlan >> 2);
  unsigned short* PSW = PS + w * 1024;

  f32x4 accY[4];
#pragma unroll
  for (int td = 0; td < 4; ++td) accY[td] = (f32x4){0.f, 0.f, 0.f, 0.f};

  // ---- phase A: s-tiles ts = 0..3 (cols 0..63) ----
  {
    f32x4 accP[4];
#pragma unroll
    for (int ts = 0; ts < 4; ++ts) accP[ts] = (f32x4){0.f, 0.f, 0.f, 0.f};
#pragma unroll
    for (int ts = 0; ts < 4; ++ts) {
      if (ts <= w) {
#pragma unroll
        for (int kb = 0; kb < 2; ++kb) {
          bf16x8 bk = ld128(KF + ((ts * 2 + kb) * 64 + (mlan * 4 + qlan)) * 8);
          accP[ts] = __builtin_amdgcn_mfma_f32_16x16x32_bf16(aq[kb], bk, accP[ts], 0, 0, 0);
        }
      }
    }
    // diagonal mask (only waves 0..3 have their diagonal in phase A)
#pragma unroll
    for (int ts = 0; ts < 4; ++ts)
      if (ts == w) {
#pragma unroll
        for (int r = 0; r < 4; ++r)
          if (mlan > qlan * 4 + r) accP[ts][r] = 0.f;
      }
    // P strip -> PS octet layout (wave-private)
#pragma unroll
    for (int ts = 0; ts < 4; ++ts)
#pragma unroll
      for (int r = 0; r < 4; ++r)
        PSW[((2 * ts + (mlan >> 3)) * 16 + 4 * qlan + r) * 8 + (mlan & 7)] =
            f2bf(accP[ts][r]);
    bf16x8 ap[2];
#pragma unroll
    for (int sb = 0; sb < 2; ++sb)
      ap[sb] = ld128(PSW + ((4 * sb + qlan) * 16 + mlan) * 8);
    // Y += P[:,0:64] V[0:64,:]
#pragma unroll
    for (int td = 0; td < 4; ++td)
#pragma unroll
      for (int sb = 0; sb < 2; ++sb) {
        bf16x8 bv = ld128(VF + ((td * 4 + sb) * 64 + rslot) * 8);
        accY[td] = __builtin_amdgcn_mfma_f32_16x16x32_bf16(ap[sb], bv, accY[td], 0, 0, 0);
      }
  }

  // ---- phase B: s-tiles ts = 4..7 (cols 64..127); causally zero for waves w<4 ----
  if (w >= 4) {
    f32x4 accP[4];
#pragma unroll
    for (int ts = 0; ts < 4; ++ts) accP[ts] = (f32x4){0.f, 0.f, 0.f, 0.f};
#pragma unroll
    for (int tsi = 0; tsi < 4; ++tsi) {
      const int ts = tsi + 4;
      if (ts <= w) {
#pragma unroll
        for (int kb = 0; kb < 2; ++kb) {
          bf16x8 bk = ld128(KF + ((ts * 2 + kb) * 64 + (mlan * 4 + qlan)) * 8);
          accP[tsi] = __builtin_amdgcn_mfma_f32_16x16x32_bf16(aq[kb], bk, accP[tsi], 0, 0, 0);
        }
      }
    }
#pragma unroll
    for (int tsi = 0; tsi < 4; ++tsi)
      if (tsi + 4 == w) {
#pragma unroll
        for (int r = 0; r < 4; ++r)
          if (mlan > qlan * 4 + r) accP[tsi][r] = 0.f;
      }
    // overwrite wave-private PS (same-wave LDS ordering guarantees correctness)
#pragma unroll
    for (int tsi = 0; tsi < 4; ++tsi)
#pragma unroll
      for (int r = 0; r < 4; ++r)
        PSW[((2 * tsi + (mlan >> 3)) * 16 + 4 * qlan + r) * 8 + (mlan & 7)] =
            f2bf(accP[tsi][r]);
    bf16x8 ap[2];
#pragma unroll
    for (int sb = 0; sb < 2; ++sb)
      ap[sb] = ld128(PSW + ((4 * sb + qlan) * 16 + mlan) * 8);
    // Y += P[:,64:128] V[64:128,:]  (VF s-blocks 2..3)
#pragma unroll
    for (int td = 0; td < 4; ++td)
#pragma unroll
      for (int sb = 0; sb < 2; ++sb) {
        bf16x8 bv = ld128(VF + ((td * 4 + 2 + sb) * 64 + rslot) * 8);
        accY[td] = __builtin_amdgcn_mfma_f32_16x16x32_bf16(ap[sb], bv, accY[td], 0, 0, 0);
      }
  }

  // matmul3: Y += Q * (Mhi + Mlo), M B-frags from swizzled LDS (64x64 tile)
  const int m7 = mlan & 7;
#pragma unroll
  for (int td = 0; td < 4; ++td)
#pragma unroll
    for (int kb = 0; kb < 2; ++kb) {
      const int mb = (16 * td + mlan) * 64 + kb * 32 + ((qlan ^ (m7 >> 1)) << 3);
      const uint4 va = *(const uint4*)(MF + mb + ((m7 & 1) << 2));        // j = 0..3
      const uint4 vb = *(const uint4*)(MF + mb + (((m7 & 1) ^ 1) << 2));  // j = 4..7
      bf16x8 bmh, bml;
      unpackM(va, vb, bmh, bml);
      accY[td] = __builtin_amdgcn_mfma_f32_16x16x32_bf16(aq[kb], bmh, accY[td], 0, 0, 0);
      accY[td] = __builtin_amdgcn_mfma_f32_16x16x32_bf16(aq[kb], bml, accY[td], 0, 0, 0);
    }

#pragma unroll
  for (int td = 0; td < 4; ++td)
#pragma unroll
    for (int r = 0; r < 4; ++r)
      yp[base + (size_t)(16 * w + 4 * qlan + r) * SROW + 16 * td + mlan] = accY[td][r];
}

extern "C" void kernel_launch(void* const* d_in, const int* in_sizes, int n_in,
                              void* d_out, int out_size, void* d_ws, size_t ws_size,
                              hipStream_t stream) {
  const float* q = (const float*)d_in[0];
  const float* k = (const float*)d_in[1];
  const float* v = (const float*)d_in[2];
  float* y = (float*)d_out;
  unsigned short* S  = (unsigned short*)d_ws;                        // 4.2 MB bf16
  unsigned*       M  = (unsigned*)((char*)d_ws + (32u << 20));       // 8.4 MB packed u32
  unsigned short* KB = (unsigned short*)((char*)d_ws + (56u << 20)); // 8.4 MB bf16 frag image
  unsigned short* VB = (unsigned short*)((char*)d_ws + (72u << 20)); // 8.4 MB bf16 frag image

  // FINAL: single pass (5x replay instrument removed).
  k_chunksum<<<BH * NC, 512, 0, stream>>>(k, v, S, KB, VB);
  k_prefix  <<<512, 256, 0, stream>>>(S, M);
  k_output  <<<BH * NC, 512, 0, stream>>>(q, KB, VB, M, y);
}